// Round 11
// baseline (82.370 us; speedup 1.0000x reference)
//
#include <hip/hip_runtime.h>
#include <hip/hip_bf16.h>
#include <stdint.h>

#define N_SRC 50000
#define N_DST 50000
#define N_EDGES 1600000
#define BATCH 64

#define DPB 32                             // dsts per bucket (5-bit dloc)
#define NBUCK ((N_DST + DPB - 1) / DPB)    // 1563
#define CAPB 1344                          // records/bucket cap (mean 1024, +10 sigma)
#define EPB 6400                           // edges per partition block (250 blocks)
#define PTHREADS 1024
#define GTHREADS 512

// ---------------------------------------------------------------------------
// Kernel 1: transpose x [BATCH, N_SRC] -> xTh [2][N_SRC][16] uint32 bf16-pairs
// (batch-half-major: half bh holds batches bh*32..bh*32+31 as 16 bf16x2).
// Each 3.2 MB half is per-XCD-L2-resident during its gather pass.
// Also zeroes the partition cursors.
// ---------------------------------------------------------------------------
__global__ void transpose_kernel(const float* __restrict__ x,
                                 uint32_t* __restrict__ xTh,
                                 int* __restrict__ gcur) {
    __shared__ float tile[64][65];
    const int s0 = blockIdx.x * 64;
    const int tid = threadIdx.x;  // 256

    if (gcur && tid < 2) {
        const int i = blockIdx.x * 2 + tid;
        if (i < NBUCK) gcur[i] = 0;
    }

#pragma unroll
    for (int it = 0; it < 16; ++it) {
        const int i = it * 256 + tid;
        const int bi = i >> 6;
        const int sc = i & 63;
        const int s = s0 + sc;
        float v = 0.0f;
        if (s < N_SRC) v = x[(size_t)bi * N_SRC + s];
        tile[bi][sc] = v;
    }
    __syncthreads();
    // 64 srcs x 32 pairs = 2048 words / 256 threads = 8 iters
#pragma unroll
    for (int it = 0; it < 8; ++it) {
        const int i = it * 256 + tid;
        const int sc = i >> 5;       // src within tile
        const int p = i & 31;        // pair index: batches 2p, 2p+1
        const int s = s0 + sc;
        if (s < N_SRC) {
            __hip_bfloat16 b0 = __float2bfloat16(tile[2 * p][sc]);
            __hip_bfloat16 b1 = __float2bfloat16(tile[2 * p + 1][sc]);
            const uint32_t val = (uint32_t)*(uint16_t*)&b0 |
                                 ((uint32_t)*(uint16_t*)&b1 << 16);
            // bh = p>>4, m = p&15
            xTh[((size_t)(p >> 4) * N_SRC + s) * 16 + (p & 15)] = val;
        }
    }
}

// ---------------------------------------------------------------------------
// Kernel 2: partition edges into fixed-capacity bucket-strided bins
// (bucket = dst >> 5). Record: k(32b) | dloc(5b@16) | src(16b).
// ---------------------------------------------------------------------------
__global__ __launch_bounds__(PTHREADS) void partition_kernel(
        const float* __restrict__ k,
        const int* __restrict__ esrc,
        const int* __restrict__ edst,
        int* __restrict__ gcur,          // NBUCK cursors, zeroed by transpose
        uint64_t* __restrict__ part) {   // NBUCK * CAPB records
    __shared__ int bcnt[NBUCK];
    __shared__ int bcur[NBUCK];
    const int e0 = blockIdx.x * EPB;
    const int n = min(EPB, N_EDGES - e0);

    for (int i = threadIdx.x; i < NBUCK; i += PTHREADS) bcnt[i] = 0;
    __syncthreads();
    for (int i = threadIdx.x; i < n; i += PTHREADS)
        atomicAdd(&bcnt[edst[e0 + i] >> 5], 1);
    __syncthreads();
    for (int bi = threadIdx.x; bi < NBUCK; bi += PTHREADS) {
        const int c = bcnt[bi];
        bcur[bi] = c ? atomicAdd(&gcur[bi], c) : 0;
    }
    __syncthreads();
    for (int i = threadIdx.x; i < n; i += PTHREADS) {
        const int e = e0 + i;
        const int d = edst[e];
        const int bkt = d >> 5;
        const int slot = atomicAdd(&bcur[bkt], 1);
        if (slot < CAPB) {
            const uint32_t lo = (uint32_t)esrc[e] | ((uint32_t)(d & 31) << 16);
            part[(size_t)bkt * CAPB + slot] =
                (uint64_t)lo | ((uint64_t)__float_as_uint(k[e]) << 32);
        }
    }
}

// ---------------------------------------------------------------------------
// Kernel 3: per-bucket gather, two-pass batch-half scheme.
// Lane = (rp = lane>>4 record slot, m = lane&15 batch-pair). Per wave-step:
// 4 records x 32 batches; 64B L2-resident xT-half read per record. Sort runs
// once; both passes accumulate in registers; staging reuses `sorted`.
// ---------------------------------------------------------------------------
__global__ __launch_bounds__(GTHREADS, 8) void gather_kernel(
        const uint32_t* __restrict__ xTh,
        const int* __restrict__ gcur,
        const uint64_t* __restrict__ part,
        const float* __restrict__ b,
        float* __restrict__ out) {
    __shared__ uint64_t raw[CAPB];
    __shared__ uint64_t sorted[CAPB];      // reused as float stg[DPB*65]
    __shared__ int dbase[DPB + 1];
    __shared__ int dcur[DPB];

    const int bk = blockIdx.x;
    const size_t base = (size_t)bk * CAPB;
    const int n = min(gcur[bk], CAPB);
    const int d0 = bk * DPB;
    const int tid = threadIdx.x;
    const int wid = tid >> 6;   // 0..7
    const int lane = tid & 63;
    const int rp = lane >> 4;   // record slot 0..3
    const int m = lane & 15;    // batch-pair within half

    if (tid < DPB) dcur[tid] = 0;
    __syncthreads();

    // single global read: stage into LDS + histogram by dloc
    for (int i = tid; i < n; i += GTHREADS) {
        const uint64_t r = part[base + i];
        raw[i] = r;
        atomicAdd(&dcur[(int)((r >> 16) & 31)], 1);
    }
    __syncthreads();

    // exclusive scan of DPB counters (wave 0, lanes 0..31)
    if (wid == 0) {
        const int orig = (lane < DPB) ? dcur[lane] : 0;
        int v = orig;
#pragma unroll
        for (int d = 1; d < DPB; d <<= 1) {
            const int t = __shfl_up(v, d, 64);
            if (lane >= d) v += t;
        }
        if (lane < DPB) dbase[lane] = v - orig;
        if (lane == DPB - 1) dbase[DPB] = v;
    }
    __syncthreads();
    if (tid < DPB) dcur[tid] = dbase[tid];
    __syncthreads();

    // scatter into sorted order (LDS -> LDS)
    for (int i = tid; i < n; i += GTHREADS) {
        const uint64_t r = raw[i];
        const int p = atomicAdd(&dcur[(int)((r >> 16) & 31)], 1);
        sorted[p] = r;
    }
    __syncthreads();

    // two passes over batch-halves; wave w owns dsts [w*4, w*4+4)
    float acc[2][4][2];
    const int dlo = wid * 4;
#pragma unroll
    for (int bh = 0; bh < 2; ++bh) {
        const uint32_t* __restrict__ xh = xTh + (size_t)bh * N_SRC * 16;
#pragma unroll
        for (int q = 0; q < 4; ++q) {
            const int dl = dlo + q;
            float px = 0.0f, py = 0.0f;
            int j = dbase[dl];
            const int je = dbase[dl + 1];
            // 2 wave-steps = 8 records per iteration
            for (; j + 8 <= je; j += 8) {
                const uint64_t r0 = sorted[j + rp];
                const uint64_t r1 = sorted[j + 4 + rp];
                const uint32_t x0 = xh[(size_t)((uint32_t)r0 & 0xFFFFu) * 16 + m];
                const uint32_t x1 = xh[(size_t)((uint32_t)r1 & 0xFFFFu) * 16 + m];
                const float k0 = __uint_as_float((uint32_t)(r0 >> 32));
                const float k1 = __uint_as_float((uint32_t)(r1 >> 32));
                px = fmaf(k0, __uint_as_float(x0 << 16), px);
                py = fmaf(k0, __uint_as_float(x0 & 0xFFFF0000u), py);
                px = fmaf(k1, __uint_as_float(x1 << 16), px);
                py = fmaf(k1, __uint_as_float(x1 & 0xFFFF0000u), py);
            }
            // tail: one wave-step (4 records), rp-guarded
            for (; j < je; j += 4) {
                const int idx = j + rp;
                const bool v = idx < je;
                const uint64_t r = sorted[v ? idx : j];
                const float kv = v ? __uint_as_float((uint32_t)(r >> 32)) : 0.0f;
                const uint32_t xv = xh[(size_t)((uint32_t)r & 0xFFFFu) * 16 + m];
                px = fmaf(kv, __uint_as_float(xv << 16), px);
                py = fmaf(kv, __uint_as_float(xv & 0xFFFF0000u), py);
            }
            // reduce across the 4 record slots
            px += __shfl_xor(px, 16);
            px += __shfl_xor(px, 32);
            py += __shfl_xor(py, 16);
            py += __shfl_xor(py, 32);
            acc[bh][q][0] = px;
            acc[bh][q][1] = py;
        }
    }
    __syncthreads();  // all waves done reading `sorted` before reuse

    // stage transposed (stride-65); lanes 0..15 (rp==0) write
    float* stg = (float*)sorted;
    if (rp == 0) {
#pragma unroll
        for (int bh = 0; bh < 2; ++bh)
#pragma unroll
            for (int q = 0; q < 4; ++q) {
                const int dl = dlo + q;
                stg[dl * 65 + bh * 32 + 2 * m]     = acc[bh][q][0];
                stg[dl * 65 + bh * 32 + 2 * m + 1] = acc[bh][q][1];
            }
    }
    __syncthreads();

    // write out[bi, d0+dl], coalesced over dl
    for (int i = tid; i < 64 * DPB; i += GTHREADS) {
        const int dl = i & (DPB - 1);
        const int bi = i >> 5;
        const int d = d0 + dl;
        if (d < N_DST)
            out[(size_t)bi * N_DST + d] = fmaxf(stg[dl * 65 + bi] + b[d], 0.0f);
    }
}

// ---------------------------------------------------------------------------
// Fallback path (atomic scatter) if ws_size too small.
// ---------------------------------------------------------------------------
__global__ void scatter_kernel(const uint32_t* __restrict__ xTh,
                               const float* __restrict__ k,
                               const int* __restrict__ esrc,
                               const int* __restrict__ edst,
                               float* __restrict__ agg) {
    const int gtid = blockIdx.x * blockDim.x + threadIdx.x;
    const int wid = gtid >> 6;
    const int lane = threadIdx.x & 63;
    const int nwaves = (gridDim.x * blockDim.x) >> 6;
    const int bh = lane >> 5, m = (lane >> 1) & 15, hi = lane & 1;
    for (int e = wid; e < N_EDGES; e += nwaves) {
        const uint32_t xv = xTh[((size_t)bh * N_SRC + esrc[e]) * 16 + m];
        const float xf = __uint_as_float(hi ? (xv & 0xFFFF0000u) : (xv << 16));
        atomicAdd(&agg[(size_t)edst[e] * 64 + lane], k[e] * xf);
    }
}

__global__ void finish_kernel(const float* __restrict__ agg,
                              const float* __restrict__ b,
                              float* __restrict__ out) {
    __shared__ float tile[64 * 65];
    const int d0 = blockIdx.x * 64;
    const int tid = threadIdx.x;
#pragma unroll
    for (int it = 0; it < 16; ++it) {
        const int i = it * 256 + tid;
        const int dl = i >> 6;
        const int bi = i & 63;
        const int d = d0 + dl;
        float v = 0.0f;
        if (d < N_DST) v = agg[(size_t)d * 64 + bi];
        tile[bi * 65 + dl] = v;
    }
    __syncthreads();
#pragma unroll
    for (int it = 0; it < 16; ++it) {
        const int i = it * 256 + tid;
        const int bi = i >> 6;
        const int dl = i & 63;
        const int d = d0 + dl;
        if (d < N_DST)
            out[(size_t)bi * N_DST + d] = fmaxf(tile[bi * 65 + dl] + b[d], 0.0f);
    }
}

extern "C" void kernel_launch(void* const* d_in, const int* in_sizes, int n_in,
                              void* d_out, int out_size, void* d_ws, size_t ws_size,
                              hipStream_t stream) {
    const float* x    = (const float*)d_in[0];
    const float* k    = (const float*)d_in[1];
    const float* b    = (const float*)d_in[2];
    const int*   esrc = (const int*)d_in[3];
    const int*   edst = (const int*)d_in[4];
    float* out = (float*)d_out;

    const size_t xt_bytes   = (size_t)2 * N_SRC * 16 * sizeof(uint32_t);     // 6.4 MB
    const size_t part_bytes = (size_t)NBUCK * CAPB * sizeof(uint64_t);       // 16.8 MB
    const size_t off_gcur   = xt_bytes + part_bytes;
    const size_t need_new   = off_gcur + ((NBUCK * 4 + 4095) & ~4095ull);    // ~23.3 MB

    uint32_t* xTh = (uint32_t*)d_ws;
    const int nblk_t = (N_SRC + 63) / 64;  // 782

    if (ws_size >= need_new) {
        uint64_t* part = (uint64_t*)((char*)d_ws + xt_bytes);
        int* gcur      = (int*)((char*)d_ws + off_gcur);

        transpose_kernel<<<nblk_t, 256, 0, stream>>>(x, xTh, gcur);
        const int nblk_p = (N_EDGES + EPB - 1) / EPB;  // 250
        partition_kernel<<<nblk_p, PTHREADS, 0, stream>>>(k, esrc, edst,
                                                          gcur, part);
        gather_kernel<<<NBUCK, GTHREADS, 0, stream>>>(xTh, gcur, part, b, out);
    } else {
        transpose_kernel<<<nblk_t, 256, 0, stream>>>(x, xTh, nullptr);
        float* agg = (float*)((char*)d_ws + ((xt_bytes + 255) & ~255ull));
        hipMemsetAsync(agg, 0, (size_t)N_DST * 64 * sizeof(float), stream);
        scatter_kernel<<<2048, 256, 0, stream>>>(xTh, k, esrc, edst, agg);
        const int nblk_f = (N_DST + 63) / 64;
        finish_kernel<<<nblk_f, 256, 0, stream>>>(agg, b, out);
    }
}

// Round 12
// 73.552 us; speedup vs baseline: 1.1199x; 1.1199x over previous
//
#include <hip/hip_runtime.h>
#include <hip/hip_bf16.h>
#include <stdint.h>

#define N_SRC 50000
#define N_DST 50000
#define N_EDGES 1600000
#define BATCH 64

#define DPB 32                             // dsts per bucket (5-bit dloc)
#define NBUCK ((N_DST + DPB - 1) / DPB)    // 1563
#define CAPB 1344                          // records/bucket cap (mean 1024, +10 sigma)
#define EPB 6400                           // edges per partition block (250 blocks)
#define PTHREADS 1024
#define GTHREADS 512

// ---------------------------------------------------------------------------
// Kernel 1: transpose x [BATCH, N_SRC] -> xTb [N_SRC, BATCH] in bf16.
// Also zeroes the partition cursors (stream-ordered before partition_kernel).
// ---------------------------------------------------------------------------
__global__ void transpose_kernel(const float* __restrict__ x,
                                 __hip_bfloat16* __restrict__ xTb,
                                 int* __restrict__ gcur) {
    __shared__ float tile[64][65];
    const int s0 = blockIdx.x * 64;
    const int tid = threadIdx.x;  // 256

    if (gcur && tid < 2) {
        const int i = blockIdx.x * 2 + tid;
        if (i < NBUCK) gcur[i] = 0;
    }

#pragma unroll
    for (int it = 0; it < 16; ++it) {
        const int i = it * 256 + tid;
        const int bi = i >> 6;
        const int sc = i & 63;
        const int s = s0 + sc;
        float v = 0.0f;
        if (s < N_SRC) v = x[(size_t)bi * N_SRC + s];
        tile[bi][sc] = v;
    }
    __syncthreads();
#pragma unroll
    for (int it = 0; it < 16; ++it) {
        const int i = it * 256 + tid;
        const int sc = i >> 6;
        const int bi = i & 63;
        const int s = s0 + sc;
        if (s < N_SRC) xTb[(size_t)s * 64 + bi] = __float2bfloat16(tile[bi][sc]);
    }
}

// ---------------------------------------------------------------------------
// Kernel 2: partition edges into fixed-capacity bucket-strided bins
// (bucket = dst >> 5). MLP-2: each thread runs two independent
// {load -> LDS-atomic -> scattered store} chains (i and i+half) so the
// latency-bound scatter phase has 2x memory-level parallelism at unchanged
// occupancy. Record: k(32b) | dloc(5b@16) | src(16b).
// ---------------------------------------------------------------------------
__global__ __launch_bounds__(PTHREADS) void partition_kernel(
        const float* __restrict__ k,
        const int* __restrict__ esrc,
        const int* __restrict__ edst,
        int* __restrict__ gcur,          // NBUCK cursors, zeroed by transpose
        uint64_t* __restrict__ part) {   // NBUCK * CAPB records
    __shared__ int bcnt[NBUCK];
    __shared__ int bcur[NBUCK];
    const int e0 = blockIdx.x * EPB;
    const int n = min(EPB, N_EDGES - e0);
    const int half = (n + 1) >> 1;

    for (int i = threadIdx.x; i < NBUCK; i += PTHREADS) bcnt[i] = 0;
    __syncthreads();

    // histogram, 2 independent chains per thread
    for (int i = threadIdx.x; i < half; i += PTHREADS) {
        const int da = edst[e0 + i];
        const bool hb = (i + half) < n;
        const int db = hb ? edst[e0 + i + half] : 0;
        atomicAdd(&bcnt[da >> 5], 1);
        if (hb) atomicAdd(&bcnt[db >> 5], 1);
    }
    __syncthreads();

    for (int bi = threadIdx.x; bi < NBUCK; bi += PTHREADS) {
        const int c = bcnt[bi];
        bcur[bi] = c ? atomicAdd(&gcur[bi], c) : 0;  // within-bucket offset
    }
    __syncthreads();

    // scatter, 2 independent chains per thread
    for (int i = threadIdx.x; i < half; i += PTHREADS) {
        const int ea = e0 + i;
        const int eb = ea + half;
        const bool hb = (i + half) < n;

        const int da = edst[ea];
        const int db = hb ? edst[eb] : 0;
        const int sa_ = esrc[ea];
        const int sb_ = hb ? esrc[eb] : 0;
        const float ka = k[ea];
        const float kb = hb ? k[eb] : 0.0f;

        const int bka = da >> 5;
        const int bkb = db >> 5;
        const int slota = atomicAdd(&bcur[bka], 1);
        const int slotb = hb ? atomicAdd(&bcur[bkb], 1) : CAPB;

        if (slota < CAPB) {
            const uint32_t lo = (uint32_t)sa_ | ((uint32_t)(da & 31) << 16);
            part[(size_t)bka * CAPB + slota] =
                (uint64_t)lo | ((uint64_t)__float_as_uint(ka) << 32);
        }
        if (hb && slotb < CAPB) {
            const uint32_t lo = (uint32_t)sb_ | ((uint32_t)(db & 31) << 16);
            part[(size_t)bkb * CAPB + slotb] =
                (uint64_t)lo | ((uint64_t)__float_as_uint(kb) << 32);
        }
    }
}

// ---------------------------------------------------------------------------
// Kernel 3: per-bucket gather, half-wave record-pair scheme (round-10 form).
// Lane = (h = lane>>5 record parity, m = lane&31 batch-pair). Each lane
// loads a bf16x2 (uint32 view of xT) and does 2 FMAs; half-waves process
// records j and j+1; one shfl_xor(32) combine per dst.
// ---------------------------------------------------------------------------
__global__ __launch_bounds__(GTHREADS, 8) void gather_kernel(
        const __hip_bfloat16* __restrict__ xTb,
        const int* __restrict__ gcur,
        const uint64_t* __restrict__ part,
        const float* __restrict__ b,
        float* __restrict__ out) {
    __shared__ uint64_t raw[CAPB];
    __shared__ uint64_t sorted[CAPB];      // reused as float stg[DPB*65]
    __shared__ int dbase[DPB + 1];
    __shared__ int dcur[DPB];

    const uint32_t* __restrict__ xTu = (const uint32_t*)xTb;  // [N_SRC][32]

    const int bk = blockIdx.x;
    const size_t base = (size_t)bk * CAPB;
    const int n = min(gcur[bk], CAPB);
    const int d0 = bk * DPB;
    const int tid = threadIdx.x;
    const int wid = tid >> 6;   // 0..7
    const int lane = tid & 63;
    const int h = lane >> 5;    // record parity within pair-step
    const int m = lane & 31;    // batch-pair index (batches 2m, 2m+1)

    if (tid < DPB) dcur[tid] = 0;
    __syncthreads();

    // single global read: stage into LDS + histogram by dloc
    for (int i = tid; i < n; i += GTHREADS) {
        const uint64_t r = part[base + i];
        raw[i] = r;
        atomicAdd(&dcur[(int)((r >> 16) & 31)], 1);
    }
    __syncthreads();

    // exclusive scan of DPB counters (wave 0, lanes 0..31)
    if (wid == 0) {
        const int orig = (lane < DPB) ? dcur[lane] : 0;
        int v = orig;
#pragma unroll
        for (int d = 1; d < DPB; d <<= 1) {
            const int t = __shfl_up(v, d, 64);
            if (lane >= d) v += t;
        }
        if (lane < DPB) dbase[lane] = v - orig;
        if (lane == DPB - 1) dbase[DPB] = v;
    }
    __syncthreads();
    if (tid < DPB) dcur[tid] = dbase[tid];
    __syncthreads();

    // scatter into sorted order (LDS -> LDS)
    for (int i = tid; i < n; i += GTHREADS) {
        const uint64_t r = raw[i];
        const int p = atomicAdd(&dcur[(int)((r >> 16) & 31)], 1);
        sorted[p] = r;
    }
    __syncthreads();

    // per-dst gather: wave w owns dsts [w*4, w*4+4); 2 records/pair-step
    float ax[4], ay[4];
    const int dlo = wid * 4;
#pragma unroll
    for (int q = 0; q < 4; ++q) {
        const int dl = dlo + q;
        const int d = d0 + dl;
        float px = 0.0f, py = 0.0f;
        if (d < N_DST) {
            int j = dbase[dl];
            const int je = dbase[dl + 1];
            // unrolled: 4 pair-steps = 8 records per iteration (MLP-8 total)
            for (; j + 8 <= je; j += 8) {
                const uint64_t r0 = sorted[j + 0 + h];
                const uint64_t r1 = sorted[j + 2 + h];
                const uint64_t r2 = sorted[j + 4 + h];
                const uint64_t r3 = sorted[j + 6 + h];
                const uint32_t x0 = xTu[(size_t)((uint32_t)r0 & 0xFFFFu) * 32 + m];
                const uint32_t x1 = xTu[(size_t)((uint32_t)r1 & 0xFFFFu) * 32 + m];
                const uint32_t x2 = xTu[(size_t)((uint32_t)r2 & 0xFFFFu) * 32 + m];
                const uint32_t x3 = xTu[(size_t)((uint32_t)r3 & 0xFFFFu) * 32 + m];
                const float k0 = __uint_as_float((uint32_t)(r0 >> 32));
                const float k1 = __uint_as_float((uint32_t)(r1 >> 32));
                const float k2 = __uint_as_float((uint32_t)(r2 >> 32));
                const float k3 = __uint_as_float((uint32_t)(r3 >> 32));
                px = fmaf(k0, __uint_as_float(x0 << 16), px);
                py = fmaf(k0, __uint_as_float(x0 & 0xFFFF0000u), py);
                px = fmaf(k1, __uint_as_float(x1 << 16), px);
                py = fmaf(k1, __uint_as_float(x1 & 0xFFFF0000u), py);
                px = fmaf(k2, __uint_as_float(x2 << 16), px);
                py = fmaf(k2, __uint_as_float(x2 & 0xFFFF0000u), py);
                px = fmaf(k3, __uint_as_float(x3 << 16), px);
                py = fmaf(k3, __uint_as_float(x3 & 0xFFFF0000u), py);
            }
            // tail: one pair-step at a time, hi-half guarded
            for (; j < je; j += 2) {
                const int idx = j + h;
                const bool v = idx < je;
                const uint64_t r = sorted[v ? idx : j];
                const float kv = v ? __uint_as_float((uint32_t)(r >> 32)) : 0.0f;
                const uint32_t xv = xTu[(size_t)((uint32_t)r & 0xFFFFu) * 32 + m];
                px = fmaf(kv, __uint_as_float(xv << 16), px);
                py = fmaf(kv, __uint_as_float(xv & 0xFFFF0000u), py);
            }
        }
        // combine the two record-parities across half-waves
        px += __shfl_xor(px, 32);
        py += __shfl_xor(py, 32);
        ax[q] = px;
        ay[q] = py;
    }
    __syncthreads();  // all waves done reading `sorted` before reuse

    // stage transposed (stride-65). lane m covers batches 2m, 2m+1.
    float* stg = (float*)sorted;
    if (h == 0) {
#pragma unroll
        for (int q = 0; q < 4; ++q) {
            const int dl = dlo + q;
            stg[dl * 65 + 2 * m]     = ax[q];
            stg[dl * 65 + 2 * m + 1] = ay[q];
        }
    }
    __syncthreads();

    // write out[bi, d0+dl], coalesced over dl
    for (int i = tid; i < 64 * DPB; i += GTHREADS) {
        const int dl = i & (DPB - 1);
        const int bi = i >> 5;
        const int d = d0 + dl;
        if (d < N_DST)
            out[(size_t)bi * N_DST + d] = fmaxf(stg[dl * 65 + bi] + b[d], 0.0f);
    }
}

// ---------------------------------------------------------------------------
// Fallback path (atomic scatter) if ws_size too small.
// ---------------------------------------------------------------------------
__global__ void scatter_kernel(const __hip_bfloat16* __restrict__ xTb,
                               const float* __restrict__ k,
                               const int* __restrict__ esrc,
                               const int* __restrict__ edst,
                               float* __restrict__ agg) {
    const int gtid = blockIdx.x * blockDim.x + threadIdx.x;
    const int wid = gtid >> 6;
    const int lane = threadIdx.x & 63;
    const int nwaves = (gridDim.x * blockDim.x) >> 6;
    for (int e = wid; e < N_EDGES; e += nwaves) {
        atomicAdd(&agg[(size_t)edst[e] * 64 + lane],
                  k[e] * __bfloat162float(xTb[(size_t)esrc[e] * 64 + lane]));
    }
}

__global__ void finish_kernel(const float* __restrict__ agg,
                              const float* __restrict__ b,
                              float* __restrict__ out) {
    __shared__ float tile[64 * 65];
    const int d0 = blockIdx.x * 64;
    const int tid = threadIdx.x;
#pragma unroll
    for (int it = 0; it < 16; ++it) {
        const int i = it * 256 + tid;
        const int dl = i >> 6;
        const int bi = i & 63;
        const int d = d0 + dl;
        float v = 0.0f;
        if (d < N_DST) v = agg[(size_t)d * 64 + bi];
        tile[bi * 65 + dl] = v;
    }
    __syncthreads();
#pragma unroll
    for (int it = 0; it < 16; ++it) {
        const int i = it * 256 + tid;
        const int bi = i >> 6;
        const int dl = i & 63;
        const int d = d0 + dl;
        if (d < N_DST)
            out[(size_t)bi * N_DST + d] = fmaxf(tile[bi * 65 + dl] + b[d], 0.0f);
    }
}

extern "C" void kernel_launch(void* const* d_in, const int* in_sizes, int n_in,
                              void* d_out, int out_size, void* d_ws, size_t ws_size,
                              hipStream_t stream) {
    const float* x    = (const float*)d_in[0];
    const float* k    = (const float*)d_in[1];
    const float* b    = (const float*)d_in[2];
    const int*   esrc = (const int*)d_in[3];
    const int*   edst = (const int*)d_in[4];
    float* out = (float*)d_out;

    const size_t xt_bytes   = (size_t)N_SRC * 64 * sizeof(__hip_bfloat16);   // 6.4 MB
    const size_t part_bytes = (size_t)NBUCK * CAPB * sizeof(uint64_t);       // 16.8 MB
    const size_t off_gcur   = xt_bytes + part_bytes;
    const size_t need_new   = off_gcur + ((NBUCK * 4 + 4095) & ~4095ull);    // ~23.3 MB

    __hip_bfloat16* xTb = (__hip_bfloat16*)d_ws;
    const int nblk_t = (N_SRC + 63) / 64;  // 782

    if (ws_size >= need_new) {
        uint64_t* part = (uint64_t*)((char*)d_ws + xt_bytes);
        int* gcur      = (int*)((char*)d_ws + off_gcur);

        transpose_kernel<<<nblk_t, 256, 0, stream>>>(x, xTb, gcur);
        const int nblk_p = (N_EDGES + EPB - 1) / EPB;  // 250
        partition_kernel<<<nblk_p, PTHREADS, 0, stream>>>(k, esrc, edst,
                                                          gcur, part);
        gather_kernel<<<NBUCK, GTHREADS, 0, stream>>>(xTb, gcur, part, b, out);
    } else {
        transpose_kernel<<<nblk_t, 256, 0, stream>>>(x, xTb, nullptr);
        float* agg = (float*)((char*)d_ws + ((xt_bytes + 255) & ~255ull));
        hipMemsetAsync(agg, 0, (size_t)N_DST * 64 * sizeof(float), stream);
        scatter_kernel<<<2048, 256, 0, stream>>>(xTb, k, esrc, edst, agg);
        const int nblk_f = (N_DST + 63) / 64;
        finish_kernel<<<nblk_f, 256, 0, stream>>>(agg, b, out);
    }
}